// Round 3
// baseline (908.879 us; speedup 1.0000x reference)
//
#include <hip/hip_runtime.h>
#include <stdint.h>

typedef unsigned long long u64;

__device__ __forceinline__ float sig_(float x) { return 1.0f / (1.0f + expf(-x)); }

#define NCAND 2535
#define NKEEP 300

// ---------------------------------------------------------------------------
// 3x3 stride-2 conv, SAME padding (pad_before=0, pad_after=1).
// OCT output channels per thread (weights wave-uniform -> s_load).
// SPLIT: deterministic split-K over input channels; SPLIT==1 writes final
// (bias + leaky-relu), SPLIT>1 writes raw partials P[s][b][oc][sp].
// Input rows loaded as float2 + 1 scalar (lane-contiguous 512B/row/wave).
// ---------------------------------------------------------------------------
template <int CIN, int HIN, int WIN, int OCT, int SPLIT>
__global__ __launch_bounds__(256) void conv3x3s2(
    const float* __restrict__ in, const float* __restrict__ wgt,
    const float* __restrict__ bias, float* __restrict__ out) {
  constexpr int HOUT = HIN / 2, WOUT = WIN / 2;
  constexpr int HWIN = HIN * WIN, HWOUT = HOUT * WOUT;
  constexpr int CS = CIN / SPLIT;
  const int b = blockIdx.z / SPLIT;
  const int s = blockIdx.z % SPLIT;
  const int oc0 = blockIdx.y * OCT;
  const int COUT = gridDim.y * OCT;
  const int sp = blockIdx.x * 256 + threadIdx.x;
  if (sp >= HWOUT) return;
  const int oy = sp / WOUT, ox = sp % WOUT;
  const int iy0 = oy * 2, ix0 = ox * 2;
  const bool okY = (iy0 + 2 < HIN);  // false only on last output row
  const bool okX = (ix0 + 2 < WIN);  // false only on last output col
  const float* inb =
      in + ((size_t)b * CIN + s * CS) * HWIN + (size_t)iy0 * WIN + ix0;
  float acc[OCT];
#pragma unroll
  for (int u = 0; u < OCT; u++) acc[u] = 0.0f;

#pragma unroll 2
  for (int ci = 0; ci < CS; ++ci) {
    const float* ip = inb + (size_t)ci * HWIN;
    float v[9];
#pragma unroll
    for (int ky = 0; ky < 3; ky++) {
      const bool rok = (ky < 2) || okY;
      const float* rp = ip + ky * WIN;
      float a0 = 0.0f, a1 = 0.0f, a2 = 0.0f;
      if (rok) {
        const float2 p = *(const float2*)rp;  // 8B-aligned: ix0,WIN,HWIN even
        a0 = p.x;
        a1 = p.y;
        if (okX) a2 = rp[2];
      }
      v[ky * 3 + 0] = a0;
      v[ky * 3 + 1] = a1;
      v[ky * 3 + 2] = a2;
    }
    const float* wp = wgt + ((size_t)oc0 * CIN + (s * CS + ci)) * 9;
#pragma unroll
    for (int u = 0; u < OCT; u++) {
#pragma unroll
      for (int k = 0; k < 9; k++)
        acc[u] = fmaf(v[k], wp[(size_t)u * CIN * 9 + k], acc[u]);
    }
  }

  if (SPLIT == 1) {
    float* ob = out + ((size_t)b * COUT + oc0) * HWOUT + sp;
#pragma unroll
    for (int u = 0; u < OCT; u++) {
      float r = acc[u] + bias[oc0 + u];
      r = r > 0.0f ? r : 0.1f * r;
      ob[(size_t)u * HWOUT] = r;
    }
  } else {
    float* ob = out + ((size_t)(s * 8 + b) * COUT + oc0) * HWOUT + sp;
#pragma unroll
    for (int u = 0; u < OCT; u++) ob[(size_t)u * HWOUT] = acc[u];
  }
}

// ---------------------------------------------------------------------------
// 1x1 conv partial (COUT=255 total), OCT channels/thread, split-K slice s.
// Writes raw partials P[s][b][oc][sp].
// ---------------------------------------------------------------------------
template <int CIN, int OCT, int SPLIT>
__global__ __launch_bounds__(256) void conv1x1_part(
    const float* __restrict__ in, const float* __restrict__ wgt,
    float* __restrict__ out, int HW) {
  constexpr int CS = CIN / SPLIT;
  const int sp = blockIdx.x * 256 + threadIdx.x;
  if (sp >= HW) return;
  const int oc0 = blockIdx.y * OCT;
  const int b = blockIdx.z / SPLIT;
  const int s = blockIdx.z % SPLIT;
  const float* ip = in + ((size_t)b * CIN + s * CS) * HW + sp;
  float acc[OCT];
#pragma unroll
  for (int u = 0; u < OCT; u++) acc[u] = 0.0f;
#pragma unroll 4
  for (int ci = 0; ci < CS; ++ci) {
    const float v = ip[(size_t)ci * HW];
#pragma unroll
    for (int u = 0; u < OCT; u++)
      acc[u] = fmaf(v, wgt[(size_t)(oc0 + u) * CIN + s * CS + ci], acc[u]);
  }
#pragma unroll
  for (int u = 0; u < OCT; u++)
    out[((size_t)(s * 8 + b) * 255 + oc0 + u) * HW + sp] = acc[u];
}

// ---------------------------------------------------------------------------
// Reduce SPLIT partials (slice-major, deterministic order) + bias
// (+ optional leaky-relu). N = 8*COUT*HWOUT elements, layout [b][oc][sp].
// ---------------------------------------------------------------------------
template <int SPLIT, bool LRELU>
__global__ __launch_bounds__(256) void reduce_bias(
    const float* __restrict__ P, const float* __restrict__ bias,
    float* __restrict__ out, int COUT, int HWOUT, int N) {
  const int gid = blockIdx.x * 256 + threadIdx.x;
  if (gid >= N) return;
  float a = 0.0f;
#pragma unroll
  for (int s = 0; s < SPLIT; s++) a += P[(size_t)s * N + gid];
  const int oc = (gid / HWOUT) % COUT;
  a += bias[oc];
  if (LRELU) a = a > 0.0f ? a : 0.1f * a;
  out[gid] = a;
}

// ---------------------------------------------------------------------------
// Decode both heads into per-candidate records AND packed sort keys.
//   cand[b][i][8] = { y1, x1, y2, x2, obj, class_conf, label, score }
//   key[b][i] = (float_bits(score) << 32) | (0xFFFFFFFF - i)
// ---------------------------------------------------------------------------
__global__ __launch_bounds__(256) void decode_kernel(
    const float* __restrict__ feat1, const float* __restrict__ feat2,
    float* __restrict__ cand, u64* __restrict__ keys) {
  const int gid = blockIdx.x * 256 + threadIdx.x;
  if (gid >= 8 * NCAND) return;
  const int b = gid / NCAND;
  const int i = gid % NCAND;
  const float* p;
  int rem, HW, W;
  float aw, ah;
  if (i < 507) {
    const int a = i / 169;
    rem = i % 169;
    HW = 169;
    W = 13;
    const float AW[3] = {81.f, 135.f, 344.f};
    const float AH[3] = {82.f, 169.f, 319.f};
    aw = AW[a];
    ah = AH[a];
    p = feat1 + ((size_t)b * 255 + a * 85) * 169 + rem;
  } else {
    const int j = i - 507;
    const int a = j / 676;
    rem = j % 676;
    HW = 676;
    W = 26;
    const float AW[3] = {10.f, 23.f, 37.f};
    const float AH[3] = {14.f, 27.f, 58.f};
    aw = AW[a];
    ah = AH[a];
    p = feat2 + ((size_t)b * 255 + a * 85) * 676 + rem;
  }
  const int gy = rem / W, gx = rem % W;
  const float invW = 1.0f / (float)W;
  float cx = (sig_(p[0]) + (float)gx) * invW;
  float cy = (sig_(p[(size_t)HW]) + (float)gy) * invW;  // H == W both heads
  float bw = expf(p[(size_t)2 * HW]) * aw / 416.0f;
  float bh = expf(p[(size_t)3 * HW]) * ah / 416.0f;
  float obj = sig_(p[(size_t)4 * HW]);
  float best = p[(size_t)5 * HW];
  int lab = 0;
  for (int c = 1; c < 80; ++c) {
    float v = p[(size_t)(5 + c) * HW];
    if (v > best) {
      best = v;
      lab = c;
    }
  }
  float cc = sig_(best);
  float score = obj * cc;
  if (score < 0.1f) score = 0.0f;
  float* o = cand + (size_t)gid * 8;
  o[0] = (cy - bh * 0.5f) * 416.0f;
  o[1] = (cx - bw * 0.5f) * 416.0f;
  o[2] = (cy + bh * 0.5f) * 416.0f;
  o[3] = (cx + bw * 0.5f) * 416.0f;
  o[4] = obj;
  o[5] = cc;
  o[6] = (float)lab;
  o[7] = score;
  keys[gid] = ((u64)__float_as_uint(score) << 32) |
              (u64)(0xFFFFFFFFu - (unsigned)i);
}

// ---------------------------------------------------------------------------
// Exact top-300 via rank (keys distinct -> bijection onto 0..NCAND-1);
// sel[rank] = idx reproduces jax.lax.top_k ordering exactly.
// ---------------------------------------------------------------------------
__global__ __launch_bounds__(256) void rank_select_kernel(
    const u64* __restrict__ keys, int* __restrict__ sel) {
  const int b = blockIdx.y;
  __shared__ u64 k[NCAND];
  const u64* kb = keys + (size_t)b * NCAND;
  for (int t = threadIdx.x; t < NCAND; t += 256) k[t] = kb[t];
  __syncthreads();
  const int idx = blockIdx.x * 256 + threadIdx.x;
  if (idx >= NCAND) return;
  const u64 me = k[idx];
  int rank = 0;
#pragma unroll 4
  for (int j = 0; j < NCAND; j++) rank += (k[j] > me) ? 1 : 0;
  if (rank < NKEEP) sel[b * NKEEP + rank] = idx;
}

// ---------------------------------------------------------------------------
// Per-image NMS: 300x300 suppression bitmask (parallel) + sequential greedy
// scan (matches fori_loop) + output [y1,x1,y2,x2,obj,cc,label] or zeros.
// ---------------------------------------------------------------------------
__global__ __launch_bounds__(256) void nms_kernel(
    const float* __restrict__ cand, const int* __restrict__ sel,
    float* __restrict__ out) {
  const int b = blockIdx.x;
  const int tid = threadIdx.x;
  const float* cb = cand + (size_t)b * NCAND * 8;

  __shared__ float bx[NKEEP][4];
  __shared__ float oc2[NKEEP][2];
  __shared__ int lb[NKEEP];
  __shared__ unsigned char validf[NKEEP];
  __shared__ u64 msk[NKEEP][5];
  __shared__ u64 keepw[5];

  for (int t = tid; t < NKEEP; t += 256) {
    const int idx = sel[b * NKEEP + t];
    const float* c = cb + (size_t)idx * 8;
    bx[t][0] = c[0];
    bx[t][1] = c[1];
    bx[t][2] = c[2];
    bx[t][3] = c[3];
    oc2[t][0] = c[4];
    oc2[t][1] = c[5];
    lb[t] = (int)c[6];
    validf[t] = (c[7] > 0.0f) ? 1 : 0;
  }
  __syncthreads();

  for (int t = tid; t < NKEEP; t += 256) {
    u64 w[5] = {0, 0, 0, 0, 0};
    if (validf[t]) {
      const float ay1 = bx[t][0], ax1 = bx[t][1], ay2 = bx[t][2], ax2 = bx[t][3];
      const float aarea = (ay2 - ay1) * (ax2 - ax1);
      const int al = lb[t];
      for (int j = 0; j < t; j++) {
        if (!validf[j] || lb[j] != al) continue;
        const float by1 = bx[j][0], bx1 = bx[j][1], by2 = bx[j][2], bx2 = bx[j][3];
        const float ty = fmaxf(ay1, by1), tx = fmaxf(ax1, bx1);
        const float ey = fminf(ay2, by2), ex = fminf(ax2, bx2);
        const float dy = fmaxf(ey - ty, 0.0f), dx = fmaxf(ex - tx, 0.0f);
        const float inter = dy * dx;
        const float barea = (by2 - by1) * (bx2 - bx1);
        const float iou = inter / (aarea + barea - inter + 1e-9f);
        if (iou > 0.5f) w[j >> 6] |= 1ull << (j & 63);
      }
    }
#pragma unroll
    for (int q = 0; q < 5; q++) msk[t][q] = w[q];
  }
  __syncthreads();

  if (tid == 0) {
    u64 kw[5] = {0, 0, 0, 0, 0};
    for (int i = 0; i < NKEEP; i++) {
      if (!validf[i]) continue;
      u64 s = 0;
#pragma unroll
      for (int q = 0; q < 5; q++) s |= msk[i][q] & kw[q];
      if (s == 0) kw[i >> 6] |= 1ull << (i & 63);
    }
#pragma unroll
    for (int q = 0; q < 5; q++) keepw[q] = kw[q];
  }
  __syncthreads();

  float* ob = out + (size_t)b * NKEEP * 7;
  for (int t = tid; t < NKEEP; t += 256) {
    const bool k = (keepw[t >> 6] >> (t & 63)) & 1ull;
    float* r = ob + (size_t)t * 7;
    if (k) {
      r[0] = bx[t][0];
      r[1] = bx[t][1];
      r[2] = bx[t][2];
      r[3] = bx[t][3];
      r[4] = oc2[t][0];
      r[5] = oc2[t][1];
      r[6] = (float)lb[t];
    } else {
      r[0] = 0.0f; r[1] = 0.0f; r[2] = 0.0f; r[3] = 0.0f;
      r[4] = 0.0f; r[5] = 0.0f; r[6] = 0.0f;
    }
  }
}

// ---------------------------------------------------------------------------
// Workspace (float offsets):
//   X1 : [0, 11075584)           8*32*208*208
//   X2 : [11075584, 16613376)    8*64*104*104
//   X3 : [0, 2768896)            (x1 dead after conv2)
//   X4 : [2768896, 4153344)
//   F2 : [4153344, 5532384)
//   X5 : [5532384, 6224608)
//   F1 : [6224608, 6569368)
//   CD : [6569368, 6731608)      8*2535*8
//   KEY: [6731608, 6772168)      8*2535 u64
//   SEL: [6772168, 6774568)      8*300 int
//   P  : [11075584, 13844480)    2768896 floats, split-K partials
//        (x2 region — dead once conv3 completes; P first used by conv4)
// Peak = 16613376 floats = 66.5 MB (unchanged).
// ---------------------------------------------------------------------------
extern "C" void kernel_launch(void* const* d_in, const int* in_sizes, int n_in,
                              void* d_out, int out_size, void* d_ws,
                              size_t ws_size, hipStream_t stream) {
  const float* images = (const float*)d_in[0];
  const float* w1 = (const float*)d_in[1];
  const float* b1 = (const float*)d_in[2];
  const float* w2 = (const float*)d_in[3];
  const float* b2 = (const float*)d_in[4];
  const float* w3 = (const float*)d_in[5];
  const float* b3 = (const float*)d_in[6];
  const float* w4 = (const float*)d_in[7];
  const float* b4 = (const float*)d_in[8];
  const float* w5 = (const float*)d_in[9];
  const float* b5 = (const float*)d_in[10];
  const float* wh1 = (const float*)d_in[11];
  const float* bh1 = (const float*)d_in[12];
  const float* wh2 = (const float*)d_in[13];
  const float* bh2 = (const float*)d_in[14];
  float* ws = (float*)d_ws;

  float* x1 = ws + 0;
  float* x2 = ws + 11075584;
  float* x3 = ws + 0;
  float* x4 = ws + 2768896;
  float* f2 = ws + 4153344;
  float* x5 = ws + 5532384;
  float* f1 = ws + 6224608;
  float* cd = ws + 6569368;
  u64* keys = (u64*)(ws + 6731608);
  int* sel = (int*)(ws + 6772168);
  float* P = ws + 11075584;

  conv3x3s2<3, 416, 416, 32, 1><<<dim3(169, 1, 8), 256, 0, stream>>>(images, w1, b1, x1);
  conv3x3s2<32, 208, 208, 32, 1><<<dim3(43, 2, 8), 256, 0, stream>>>(x1, w2, b2, x2);
  conv3x3s2<64, 104, 104, 16, 1><<<dim3(11, 8, 8), 256, 0, stream>>>(x2, w3, b3, x3);

  // conv4: split-K x2 -> 768 blocks, then reduce+bias+lrelu.
  conv3x3s2<128, 52, 52, 16, 2><<<dim3(3, 16, 16), 256, 0, stream>>>(x3, w4, nullptr, P);
  reduce_bias<2, true><<<(1384448 + 255) / 256, 256, 0, stream>>>(P, b4, x4, 256, 676, 1384448);

  // head2: split-K x2 -> 720 blocks.
  conv1x1_part<256, 17, 2><<<dim3(3, 15, 16), 256, 0, stream>>>(x4, wh2, P, 676);
  reduce_bias<2, false><<<(1379040 + 255) / 256, 256, 0, stream>>>(P, bh2, f2, 255, 676, 1379040);

  // conv5: split-K x4 -> 1024 blocks.
  conv3x3s2<256, 26, 26, 16, 4><<<dim3(1, 32, 32), 256, 0, stream>>>(x4, w5, nullptr, P);
  reduce_bias<4, true><<<(692224 + 255) / 256, 256, 0, stream>>>(P, b5, x5, 512, 169, 692224);

  // head1: split-K x4 -> 544 blocks.
  conv1x1_part<512, 15, 4><<<dim3(1, 17, 32), 256, 0, stream>>>(x5, wh1, P, 169);
  reduce_bias<4, false><<<(344760 + 255) / 256, 256, 0, stream>>>(P, bh1, f1, 255, 169, 344760);

  decode_kernel<<<80, 256, 0, stream>>>(f1, f2, cd, keys);
  rank_select_kernel<<<dim3(10, 8), 256, 0, stream>>>(keys, sel);
  nms_kernel<<<8, 256, 0, stream>>>(cd, sel, (float*)d_out);
}

// Round 4
// 711.244 us; speedup vs baseline: 1.2779x; 1.2779x over previous
//
#include <hip/hip_runtime.h>
#include <stdint.h>

typedef unsigned long long u64;

__device__ __forceinline__ float sig_(float x) { return 1.0f / (1.0f + expf(-x)); }

#define NCAND 2535
#define NKEEP 300

// Load the 3x3 stride-2 window (float2 + scalar per row), zero-predicated at
// the bottom/right SAME-padding edge.
template <int WIN>
__device__ __forceinline__ void load9(float v[9], const float* __restrict__ ip,
                                      bool okY, bool okX) {
#pragma unroll
  for (int ky = 0; ky < 3; ky++) {
    const bool rok = (ky < 2) || okY;
    const float* rp = ip + ky * WIN;
    float a0 = 0.0f, a1 = 0.0f, a2 = 0.0f;
    if (rok) {
      const float2 p = *(const float2*)rp;  // 8B-aligned (ix0, WIN, HWIN even)
      a0 = p.x;
      a1 = p.y;
      if (okX) a2 = rp[2];
    }
    v[ky * 3 + 0] = a0;
    v[ky * 3 + 1] = a1;
    v[ky * 3 + 2] = a2;
  }
}

// ---------------------------------------------------------------------------
// 3x3 stride-2 conv, SAME padding (pad 0 before / 1 after), OCT out-channels
// per thread, deterministic split-K (SPLIT>1 -> raw partials P[s][b][oc][sp]).
// Register double-buffer: ci+1's window loads issue BEFORE ci's FMA block so
// the waitcnt lands after ~2*OCT*9 cycles of FMA.
// ---------------------------------------------------------------------------
template <int CIN, int HIN, int WIN, int OCT, int SPLIT>
__global__ __launch_bounds__(256) void conv3x3s2(
    const float* __restrict__ in, const float* __restrict__ wgt,
    const float* __restrict__ bias, float* __restrict__ out) {
  constexpr int HOUT = HIN / 2, WOUT = WIN / 2;
  constexpr int HWIN = HIN * WIN, HWOUT = HOUT * WOUT;
  constexpr int CS = CIN / SPLIT;
  const int b = blockIdx.z / SPLIT;
  const int s = blockIdx.z % SPLIT;
  const int oc0 = blockIdx.y * OCT;
  const int COUT = gridDim.y * OCT;
  const int sp = blockIdx.x * 256 + threadIdx.x;
  if (sp >= HWOUT) return;
  const int oy = sp / WOUT, ox = sp % WOUT;
  const int iy0 = oy * 2, ix0 = ox * 2;
  const bool okY = (iy0 + 2 < HIN);
  const bool okX = (ix0 + 2 < WIN);
  const float* inb =
      in + ((size_t)b * CIN + s * CS) * HWIN + (size_t)iy0 * WIN + ix0;
  const float* wbase = wgt + ((size_t)oc0 * CIN + s * CS) * 9;

  float acc[OCT];
#pragma unroll
  for (int u = 0; u < OCT; u++) acc[u] = 0.0f;

  float cur[9];
  load9<WIN>(cur, inb, okY, okX);

  for (int ci = 0; ci < CS; ++ci) {
    float nxt[9];
    const bool more = (ci + 1 < CS);
    if (more) load9<WIN>(nxt, inb + (size_t)(ci + 1) * HWIN, okY, okX);
    const float* wp = wbase + (size_t)ci * 9;
#pragma unroll
    for (int u = 0; u < OCT; u++) {
#pragma unroll
      for (int k = 0; k < 9; k++)
        acc[u] = fmaf(cur[k], wp[(size_t)u * CIN * 9 + k], acc[u]);
    }
    if (more) {
#pragma unroll
      for (int k = 0; k < 9; k++) cur[k] = nxt[k];
    }
  }

  if (SPLIT == 1) {
    float* ob = out + ((size_t)b * COUT + oc0) * HWOUT + sp;
#pragma unroll
    for (int u = 0; u < OCT; u++) {
      float r = acc[u] + bias[oc0 + u];
      r = r > 0.0f ? r : 0.1f * r;
      ob[(size_t)u * HWOUT] = r;
    }
  } else {
    float* ob = out + ((size_t)(s * 8 + b) * COUT + oc0) * HWOUT + sp;
#pragma unroll
    for (int u = 0; u < OCT; u++) ob[(size_t)u * HWOUT] = acc[u];
  }
}

// ---------------------------------------------------------------------------
// 1x1 conv partials (COUT=255 total), OCT ch/thread, split-K slice s.
// Register double-buffer with depth-4 channel chunks.
// ---------------------------------------------------------------------------
template <int CIN, int OCT, int SPLIT>
__global__ __launch_bounds__(256) void conv1x1_part(
    const float* __restrict__ in, const float* __restrict__ wgt,
    float* __restrict__ out, int HW) {
  constexpr int CS = CIN / SPLIT;  // multiple of 4 for all uses
  const int sp = blockIdx.x * 256 + threadIdx.x;
  if (sp >= HW) return;
  const int oc0 = blockIdx.y * OCT;
  const int b = blockIdx.z / SPLIT;
  const int s = blockIdx.z % SPLIT;
  const float* ip = in + ((size_t)b * CIN + s * CS) * HW + sp;
  const float* wb = wgt + s * CS;
  float acc[OCT];
#pragma unroll
  for (int u = 0; u < OCT; u++) acc[u] = 0.0f;

  float cur[4];
#pragma unroll
  for (int j = 0; j < 4; j++) cur[j] = ip[(size_t)j * HW];

  for (int c0 = 0; c0 < CS; c0 += 4) {
    float nxt[4];
    const bool more = (c0 + 4 < CS);
    if (more) {
#pragma unroll
      for (int j = 0; j < 4; j++) nxt[j] = ip[(size_t)(c0 + 4 + j) * HW];
    }
#pragma unroll
    for (int j = 0; j < 4; j++) {
#pragma unroll
      for (int u = 0; u < OCT; u++)
        acc[u] = fmaf(cur[j], wb[(size_t)(oc0 + u) * CIN + c0 + j], acc[u]);
    }
    if (more) {
#pragma unroll
      for (int j = 0; j < 4; j++) cur[j] = nxt[j];
    }
  }
#pragma unroll
  for (int u = 0; u < OCT; u++)
    out[((size_t)(s * 8 + b) * 255 + oc0 + u) * HW + sp] = acc[u];
}

// ---------------------------------------------------------------------------
// Reduce SPLIT partials (slice-major, deterministic) + bias (+ lrelu).
// ---------------------------------------------------------------------------
template <int SPLIT, bool LRELU>
__global__ __launch_bounds__(256) void reduce_bias(
    const float* __restrict__ P, const float* __restrict__ bias,
    float* __restrict__ out, int COUT, int HWOUT, int N) {
  const int gid = blockIdx.x * 256 + threadIdx.x;
  if (gid >= N) return;
  float a = 0.0f;
#pragma unroll
  for (int s = 0; s < SPLIT; s++) a += P[(size_t)s * N + gid];
  const int oc = (gid / HWOUT) % COUT;
  a += bias[oc];
  if (LRELU) a = a > 0.0f ? a : 0.1f * a;
  out[gid] = a;
}

// ---------------------------------------------------------------------------
// Decode both heads -> cand[b][i][8] = {y1,x1,y2,x2,obj,cc,label,score} and
// packed keys (score_bits<<32)|(0xFFFFFFFF-i) matching jax.lax.top_k order.
// ---------------------------------------------------------------------------
__global__ __launch_bounds__(256) void decode_kernel(
    const float* __restrict__ feat1, const float* __restrict__ feat2,
    float* __restrict__ cand, u64* __restrict__ keys) {
  const int gid = blockIdx.x * 256 + threadIdx.x;
  if (gid >= 8 * NCAND) return;
  const int b = gid / NCAND;
  const int i = gid % NCAND;
  const float* p;
  int rem, HW, W;
  float aw, ah;
  if (i < 507) {
    const int a = i / 169;
    rem = i % 169;
    HW = 169;
    W = 13;
    const float AW[3] = {81.f, 135.f, 344.f};
    const float AH[3] = {82.f, 169.f, 319.f};
    aw = AW[a];
    ah = AH[a];
    p = feat1 + ((size_t)b * 255 + a * 85) * 169 + rem;
  } else {
    const int j = i - 507;
    const int a = j / 676;
    rem = j % 676;
    HW = 676;
    W = 26;
    const float AW[3] = {10.f, 23.f, 37.f};
    const float AH[3] = {14.f, 27.f, 58.f};
    aw = AW[a];
    ah = AH[a];
    p = feat2 + ((size_t)b * 255 + a * 85) * 676 + rem;
  }
  const int gy = rem / W, gx = rem % W;
  const float invW = 1.0f / (float)W;
  float cx = (sig_(p[0]) + (float)gx) * invW;
  float cy = (sig_(p[(size_t)HW]) + (float)gy) * invW;
  float bw = expf(p[(size_t)2 * HW]) * aw / 416.0f;
  float bh = expf(p[(size_t)3 * HW]) * ah / 416.0f;
  float obj = sig_(p[(size_t)4 * HW]);
  float best = p[(size_t)5 * HW];
  int lab = 0;
  for (int c = 1; c < 80; ++c) {
    float v = p[(size_t)(5 + c) * HW];
    if (v > best) {
      best = v;
      lab = c;
    }
  }
  float cc = sig_(best);
  float score = obj * cc;
  if (score < 0.1f) score = 0.0f;
  float* o = cand + (size_t)gid * 8;
  o[0] = (cy - bh * 0.5f) * 416.0f;
  o[1] = (cx - bw * 0.5f) * 416.0f;
  o[2] = (cy + bh * 0.5f) * 416.0f;
  o[3] = (cx + bw * 0.5f) * 416.0f;
  o[4] = obj;
  o[5] = cc;
  o[6] = (float)lab;
  o[7] = score;
  keys[gid] = ((u64)__float_as_uint(score) << 32) |
              (u64)(0xFFFFFFFFu - (unsigned)i);
}

// ---------------------------------------------------------------------------
// Exact top-300 via rank (distinct keys -> bijection): sel[rank]=idx.
// ---------------------------------------------------------------------------
__global__ __launch_bounds__(256) void rank_select_kernel(
    const u64* __restrict__ keys, int* __restrict__ sel) {
  const int b = blockIdx.y;
  __shared__ u64 k[NCAND];
  const u64* kb = keys + (size_t)b * NCAND;
  for (int t = threadIdx.x; t < NCAND; t += 256) k[t] = kb[t];
  __syncthreads();
  const int idx = blockIdx.x * 256 + threadIdx.x;
  if (idx >= NCAND) return;
  const u64 me = k[idx];
  int rank = 0;
#pragma unroll 4
  for (int j = 0; j < NCAND; j++) rank += (k[j] > me) ? 1 : 0;
  if (rank < NKEEP) sel[b * NKEEP + rank] = idx;
}

// ---------------------------------------------------------------------------
// Per-image NMS: parallel 300x300 suppression bitmask + sequential greedy
// scan (matches the fori_loop) + output write.
// ---------------------------------------------------------------------------
__global__ __launch_bounds__(256) void nms_kernel(
    const float* __restrict__ cand, const int* __restrict__ sel,
    float* __restrict__ out) {
  const int b = blockIdx.x;
  const int tid = threadIdx.x;
  const float* cb = cand + (size_t)b * NCAND * 8;

  __shared__ float bx[NKEEP][4];
  __shared__ float oc2[NKEEP][2];
  __shared__ int lb[NKEEP];
  __shared__ unsigned char validf[NKEEP];
  __shared__ u64 msk[NKEEP][5];
  __shared__ u64 keepw[5];

  for (int t = tid; t < NKEEP; t += 256) {
    const int idx = sel[b * NKEEP + t];
    const float* c = cb + (size_t)idx * 8;
    bx[t][0] = c[0];
    bx[t][1] = c[1];
    bx[t][2] = c[2];
    bx[t][3] = c[3];
    oc2[t][0] = c[4];
    oc2[t][1] = c[5];
    lb[t] = (int)c[6];
    validf[t] = (c[7] > 0.0f) ? 1 : 0;
  }
  __syncthreads();

  for (int t = tid; t < NKEEP; t += 256) {
    u64 w[5] = {0, 0, 0, 0, 0};
    if (validf[t]) {
      const float ay1 = bx[t][0], ax1 = bx[t][1], ay2 = bx[t][2], ax2 = bx[t][3];
      const float aarea = (ay2 - ay1) * (ax2 - ax1);
      const int al = lb[t];
      for (int j = 0; j < t; j++) {
        if (!validf[j] || lb[j] != al) continue;
        const float by1 = bx[j][0], bx1 = bx[j][1], by2 = bx[j][2], bx2 = bx[j][3];
        const float ty = fmaxf(ay1, by1), tx = fmaxf(ax1, bx1);
        const float ey = fminf(ay2, by2), ex = fminf(ax2, bx2);
        const float dy = fmaxf(ey - ty, 0.0f), dx = fmaxf(ex - tx, 0.0f);
        const float inter = dy * dx;
        const float barea = (by2 - by1) * (bx2 - bx1);
        const float iou = inter / (aarea + barea - inter + 1e-9f);
        if (iou > 0.5f) w[j >> 6] |= 1ull << (j & 63);
      }
    }
#pragma unroll
    for (int q = 0; q < 5; q++) msk[t][q] = w[q];
  }
  __syncthreads();

  if (tid == 0) {
    u64 kw[5] = {0, 0, 0, 0, 0};
    for (int i = 0; i < NKEEP; i++) {
      if (!validf[i]) continue;
      u64 s = 0;
#pragma unroll
      for (int q = 0; q < 5; q++) s |= msk[i][q] & kw[q];
      if (s == 0) kw[i >> 6] |= 1ull << (i & 63);
    }
#pragma unroll
    for (int q = 0; q < 5; q++) keepw[q] = kw[q];
  }
  __syncthreads();

  float* ob = out + (size_t)b * NKEEP * 7;
  for (int t = tid; t < NKEEP; t += 256) {
    const bool k = (keepw[t >> 6] >> (t & 63)) & 1ull;
    float* r = ob + (size_t)t * 7;
    if (k) {
      r[0] = bx[t][0];
      r[1] = bx[t][1];
      r[2] = bx[t][2];
      r[3] = bx[t][3];
      r[4] = oc2[t][0];
      r[5] = oc2[t][1];
      r[6] = (float)lb[t];
    } else {
      r[0] = 0.0f; r[1] = 0.0f; r[2] = 0.0f; r[3] = 0.0f;
      r[4] = 0.0f; r[5] = 0.0f; r[6] = 0.0f;
    }
  }
}

// ---------------------------------------------------------------------------
// Workspace (float offsets):
//   X1 : [0, 11075584)         8*32*208*208
//   X2 : [11075584, 16613376)  8*64*104*104  (region reused as P afterwards)
//   X3 : [0, 2768896)
//   X4 : [2768896, 4153344)
//   F2 : [4153344, 5532384)
//   X5 : [5532384, 6224608)
//   F1 : [6224608, 6569368)
//   CD : [6569368, 6731608)
//   KEY: [6731608, 6772168)
//   SEL: [6772168, 6774568)
//   P  : [11075584, +5537792)  max partials use = 5,516,160 floats (head2 x4)
// Peak = 16613376 floats = 66.5 MB.
// ---------------------------------------------------------------------------
extern "C" void kernel_launch(void* const* d_in, const int* in_sizes, int n_in,
                              void* d_out, int out_size, void* d_ws,
                              size_t ws_size, hipStream_t stream) {
  const float* images = (const float*)d_in[0];
  const float* w1 = (const float*)d_in[1];
  const float* b1 = (const float*)d_in[2];
  const float* w2 = (const float*)d_in[3];
  const float* b2 = (const float*)d_in[4];
  const float* w3 = (const float*)d_in[5];
  const float* b3 = (const float*)d_in[6];
  const float* w4 = (const float*)d_in[7];
  const float* b4 = (const float*)d_in[8];
  const float* w5 = (const float*)d_in[9];
  const float* b5 = (const float*)d_in[10];
  const float* wh1 = (const float*)d_in[11];
  const float* bh1 = (const float*)d_in[12];
  const float* wh2 = (const float*)d_in[13];
  const float* bh2 = (const float*)d_in[14];
  float* ws = (float*)d_ws;

  float* x1 = ws + 0;
  float* x2 = ws + 11075584;
  float* x3 = ws + 0;
  float* x4 = ws + 2768896;
  float* f2 = ws + 4153344;
  float* x5 = ws + 5532384;
  float* f1 = ws + 6224608;
  float* cd = ws + 6569368;
  u64* keys = (u64*)(ws + 6731608);
  int* sel = (int*)(ws + 6772168);
  float* P = ws + 11075584;

  // conv1: 2704 blocks
  conv3x3s2<3, 416, 416, 16, 1><<<dim3(169, 2, 8), 256, 0, stream>>>(images, w1, b1, x1);
  // conv2: 1376 blocks
  conv3x3s2<32, 208, 208, 16, 1><<<dim3(43, 4, 8), 256, 0, stream>>>(x1, w2, b2, x2);
  // conv3: 1408 blocks
  conv3x3s2<64, 104, 104, 8, 1><<<dim3(11, 16, 8), 256, 0, stream>>>(x2, w3, b3, x3);
  // conv4: split-K x2 -> 1536 blocks
  conv3x3s2<128, 52, 52, 8, 2><<<dim3(3, 32, 16), 256, 0, stream>>>(x3, w4, nullptr, P);
  reduce_bias<2, true><<<(1384448 + 255) / 256, 256, 0, stream>>>(P, b4, x4, 256, 676, 1384448);
  // head2: split-K x4 -> 1440 blocks
  conv1x1_part<256, 17, 4><<<dim3(3, 15, 32), 256, 0, stream>>>(x4, wh2, P, 676);
  reduce_bias<4, false><<<(1379040 + 255) / 256, 256, 0, stream>>>(P, bh2, f2, 255, 676, 1379040);
  // conv5: split-K x4 -> 2048 blocks
  conv3x3s2<256, 26, 26, 8, 4><<<dim3(1, 64, 32), 256, 0, stream>>>(x4, w5, nullptr, P);
  reduce_bias<4, true><<<(692224 + 255) / 256, 256, 0, stream>>>(P, b5, x5, 512, 169, 692224);
  // head1: split-K x8 -> 960 blocks
  conv1x1_part<512, 17, 8><<<dim3(1, 15, 64), 256, 0, stream>>>(x5, wh1, P, 169);
  reduce_bias<8, false><<<(344760 + 255) / 256, 256, 0, stream>>>(P, bh1, f1, 255, 169, 344760);

  decode_kernel<<<80, 256, 0, stream>>>(f1, f2, cd, keys);
  rank_select_kernel<<<dim3(10, 8), 256, 0, stream>>>(keys, sel);
  nms_kernel<<<8, 256, 0, stream>>>(cd, sel, (float*)d_out);
}

// Round 5
// 661.720 us; speedup vs baseline: 1.3735x; 1.0748x over previous
//
#include <hip/hip_runtime.h>
#include <stdint.h>

typedef unsigned long long u64;

__device__ __forceinline__ float sig_(float x) { return 1.0f / (1.0f + expf(-x)); }

#define NCAND 2535
#define NKEEP 300

// ---------------------------------------------------------------------------
// Pair-spatial 3x3 stride-2 conv (2 horizontal outputs/thread), SAME padding
// (0 before / 1 after), OCT out-channels/thread, deterministic split-K.
// Window = 3 rows x 5 cols (adjacent windows share a column); rows loaded as
// aligned float4 + predicated scalar. Register double-buffer over ci.
// Requires WOUT even and WIN % 4 == 0 (true for conv1..conv4).
// ---------------------------------------------------------------------------
template <int CIN, int HIN, int WIN, int OCT, int SPLIT>
__global__ __launch_bounds__(256) void conv3x3s2_p2(
    const float* __restrict__ in, const float* __restrict__ wgt,
    const float* __restrict__ bias, float* __restrict__ out) {
  constexpr int HOUT = HIN / 2, WOUT = WIN / 2;
  constexpr int WP = WOUT / 2;  // pairs per row (WOUT even)
  constexpr int HWIN = HIN * WIN, HWOUT = HOUT * WOUT;
  constexpr int CS = CIN / SPLIT;
  static_assert(WOUT % 2 == 0 && WIN % 4 == 0, "pair kernel layout");
  const int b = blockIdx.z / SPLIT;
  const int s = blockIdx.z % SPLIT;
  const int oc0 = blockIdx.y * OCT;
  const int COUT = gridDim.y * OCT;
  const int sp = blockIdx.x * 256 + threadIdx.x;
  if (sp >= HOUT * WP) return;
  const int oy = sp / WP, oxp = sp % WP;
  const int ox0 = oxp * 2;
  const int iy0 = oy * 2, ix0 = oxp * 4;
  const bool okY = (iy0 + 2 < HIN);   // last output row -> bottom pad
  const bool c4v = (ix0 + 4 < WIN);   // last pair -> right pad for out1
  const float* inb =
      in + ((size_t)b * CIN + s * CS) * HWIN + (size_t)iy0 * WIN + ix0;
  const float* wbase = wgt + ((size_t)oc0 * CIN + s * CS) * 9;

  float acc0[OCT], acc1[OCT];
#pragma unroll
  for (int u = 0; u < OCT; u++) {
    acc0[u] = 0.0f;
    acc1[u] = 0.0f;
  }

  auto load15 = [&](float v[15], const float* ip) {
#pragma unroll
    for (int ky = 0; ky < 3; ky++) {
      const bool rok = (ky < 2) || okY;
      const float* rp = ip + ky * WIN;
      float4 p = make_float4(0.f, 0.f, 0.f, 0.f);
      float c4 = 0.f;
      if (rok) {
        p = *(const float4*)rp;  // 16B-aligned: ix0%4==0, WIN%4==0
        if (c4v) c4 = rp[4];
      }
      v[ky * 5 + 0] = p.x;
      v[ky * 5 + 1] = p.y;
      v[ky * 5 + 2] = p.z;
      v[ky * 5 + 3] = p.w;
      v[ky * 5 + 4] = c4;
    }
  };

  float cur[15];
  load15(cur, inb);

  for (int ci = 0; ci < CS; ++ci) {
    float nxt[15];
    const bool more = (ci + 1 < CS);
    if (more) load15(nxt, inb + (size_t)(ci + 1) * HWIN);
    const float* wp = wbase + (size_t)ci * 9;
#pragma unroll
    for (int u = 0; u < OCT; u++) {
#pragma unroll
      for (int ky = 0; ky < 3; ky++) {
#pragma unroll
        for (int kx = 0; kx < 3; kx++) {
          const float w = wp[(size_t)u * CIN * 9 + ky * 3 + kx];
          acc0[u] = fmaf(cur[ky * 5 + kx], w, acc0[u]);
          acc1[u] = fmaf(cur[ky * 5 + kx + 2], w, acc1[u]);
        }
      }
    }
    if (more) {
#pragma unroll
      for (int k = 0; k < 15; k++) cur[k] = nxt[k];
    }
  }

  const size_t obase =
      (SPLIT == 1 ? (size_t)b * COUT : (size_t)(s * 8 + b) * COUT);
  float* ob = out + (obase + oc0) * HWOUT + (size_t)oy * WOUT + ox0;
  if (SPLIT == 1) {
#pragma unroll
    for (int u = 0; u < OCT; u++) {
      float r0 = acc0[u] + bias[oc0 + u];
      float r1 = acc1[u] + bias[oc0 + u];
      r0 = r0 > 0.0f ? r0 : 0.1f * r0;
      r1 = r1 > 0.0f ? r1 : 0.1f * r1;
      *(float2*)(ob + (size_t)u * HWOUT) = make_float2(r0, r1);
    }
  } else {
#pragma unroll
    for (int u = 0; u < OCT; u++)
      *(float2*)(ob + (size_t)u * HWOUT) = make_float2(acc0[u], acc1[u]);
  }
}

// ---------------------------------------------------------------------------
// Single-spatial 3x3 stride-2 conv (used for conv5: WOUT=13 odd).
// ---------------------------------------------------------------------------
template <int WIN>
__device__ __forceinline__ void load9(float v[9], const float* __restrict__ ip,
                                      bool okY, bool okX) {
#pragma unroll
  for (int ky = 0; ky < 3; ky++) {
    const bool rok = (ky < 2) || okY;
    const float* rp = ip + ky * WIN;
    float a0 = 0.0f, a1 = 0.0f, a2 = 0.0f;
    if (rok) {
      const float2 p = *(const float2*)rp;  // 8B-aligned
      a0 = p.x;
      a1 = p.y;
      if (okX) a2 = rp[2];
    }
    v[ky * 3 + 0] = a0;
    v[ky * 3 + 1] = a1;
    v[ky * 3 + 2] = a2;
  }
}

template <int CIN, int HIN, int WIN, int OCT, int SPLIT>
__global__ __launch_bounds__(256) void conv3x3s2(
    const float* __restrict__ in, const float* __restrict__ wgt,
    const float* __restrict__ bias, float* __restrict__ out) {
  constexpr int HOUT = HIN / 2, WOUT = WIN / 2;
  constexpr int HWIN = HIN * WIN, HWOUT = HOUT * WOUT;
  constexpr int CS = CIN / SPLIT;
  const int b = blockIdx.z / SPLIT;
  const int s = blockIdx.z % SPLIT;
  const int oc0 = blockIdx.y * OCT;
  const int COUT = gridDim.y * OCT;
  const int sp = blockIdx.x * 256 + threadIdx.x;
  if (sp >= HWOUT) return;
  const int oy = sp / WOUT, ox = sp % WOUT;
  const int iy0 = oy * 2, ix0 = ox * 2;
  const bool okY = (iy0 + 2 < HIN);
  const bool okX = (ix0 + 2 < WIN);
  const float* inb =
      in + ((size_t)b * CIN + s * CS) * HWIN + (size_t)iy0 * WIN + ix0;
  const float* wbase = wgt + ((size_t)oc0 * CIN + s * CS) * 9;

  float acc[OCT];
#pragma unroll
  for (int u = 0; u < OCT; u++) acc[u] = 0.0f;

  float cur[9];
  load9<WIN>(cur, inb, okY, okX);

  for (int ci = 0; ci < CS; ++ci) {
    float nxt[9];
    const bool more = (ci + 1 < CS);
    if (more) load9<WIN>(nxt, inb + (size_t)(ci + 1) * HWIN, okY, okX);
    const float* wp = wbase + (size_t)ci * 9;
#pragma unroll
    for (int u = 0; u < OCT; u++) {
#pragma unroll
      for (int k = 0; k < 9; k++)
        acc[u] = fmaf(cur[k], wp[(size_t)u * CIN * 9 + k], acc[u]);
    }
    if (more) {
#pragma unroll
      for (int k = 0; k < 9; k++) cur[k] = nxt[k];
    }
  }

  if (SPLIT == 1) {
    float* ob = out + ((size_t)b * COUT + oc0) * HWOUT + sp;
#pragma unroll
    for (int u = 0; u < OCT; u++) {
      float r = acc[u] + bias[oc0 + u];
      r = r > 0.0f ? r : 0.1f * r;
      ob[(size_t)u * HWOUT] = r;
    }
  } else {
    float* ob = out + ((size_t)(s * 8 + b) * COUT + oc0) * HWOUT + sp;
#pragma unroll
    for (int u = 0; u < OCT; u++) ob[(size_t)u * HWOUT] = acc[u];
  }
}

// ---------------------------------------------------------------------------
// 1x1 conv partials (COUT=255 total), OCT ch/thread, split-K slice s.
// ---------------------------------------------------------------------------
template <int CIN, int OCT, int SPLIT>
__global__ __launch_bounds__(256) void conv1x1_part(
    const float* __restrict__ in, const float* __restrict__ wgt,
    float* __restrict__ out, int HW) {
  constexpr int CS = CIN / SPLIT;
  const int sp = blockIdx.x * 256 + threadIdx.x;
  if (sp >= HW) return;
  const int oc0 = blockIdx.y * OCT;
  const int b = blockIdx.z / SPLIT;
  const int s = blockIdx.z % SPLIT;
  const float* ip = in + ((size_t)b * CIN + s * CS) * HW + sp;
  const float* wb = wgt + s * CS;
  float acc[OCT];
#pragma unroll
  for (int u = 0; u < OCT; u++) acc[u] = 0.0f;

  float cur[4];
#pragma unroll
  for (int j = 0; j < 4; j++) cur[j] = ip[(size_t)j * HW];

  for (int c0 = 0; c0 < CS; c0 += 4) {
    float nxt[4];
    const bool more = (c0 + 4 < CS);
    if (more) {
#pragma unroll
      for (int j = 0; j < 4; j++) nxt[j] = ip[(size_t)(c0 + 4 + j) * HW];
    }
#pragma unroll
    for (int j = 0; j < 4; j++) {
#pragma unroll
      for (int u = 0; u < OCT; u++)
        acc[u] = fmaf(cur[j], wb[(size_t)(oc0 + u) * CIN + c0 + j], acc[u]);
    }
    if (more) {
#pragma unroll
      for (int j = 0; j < 4; j++) cur[j] = nxt[j];
    }
  }
#pragma unroll
  for (int u = 0; u < OCT; u++)
    out[((size_t)(s * 8 + b) * 255 + oc0 + u) * HW + sp] = acc[u];
}

// ---------------------------------------------------------------------------
// Reduce SPLIT partials (slice-major, deterministic) + bias (+ lrelu).
// ---------------------------------------------------------------------------
template <int SPLIT, bool LRELU>
__global__ __launch_bounds__(256) void reduce_bias(
    const float* __restrict__ P, const float* __restrict__ bias,
    float* __restrict__ out, int COUT, int HWOUT, int N) {
  const int gid = blockIdx.x * 256 + threadIdx.x;
  if (gid >= N) return;
  float a = 0.0f;
#pragma unroll
  for (int s = 0; s < SPLIT; s++) a += P[(size_t)s * N + gid];
  const int oc = (gid / HWOUT) % COUT;
  a += bias[oc];
  if (LRELU) a = a > 0.0f ? a : 0.1f * a;
  out[gid] = a;
}

// ---------------------------------------------------------------------------
// Decode both heads -> cand[b][i][8] = {y1,x1,y2,x2,obj,cc,label,score} and
// packed keys (score_bits<<32)|(0xFFFFFFFF-i) matching jax.lax.top_k order.
// ---------------------------------------------------------------------------
__global__ __launch_bounds__(256) void decode_kernel(
    const float* __restrict__ feat1, const float* __restrict__ feat2,
    float* __restrict__ cand, u64* __restrict__ keys) {
  const int gid = blockIdx.x * 256 + threadIdx.x;
  if (gid >= 8 * NCAND) return;
  const int b = gid / NCAND;
  const int i = gid % NCAND;
  const float* p;
  int rem, HW, W;
  float aw, ah;
  if (i < 507) {
    const int a = i / 169;
    rem = i % 169;
    HW = 169;
    W = 13;
    const float AW[3] = {81.f, 135.f, 344.f};
    const float AH[3] = {82.f, 169.f, 319.f};
    aw = AW[a];
    ah = AH[a];
    p = feat1 + ((size_t)b * 255 + a * 85) * 169 + rem;
  } else {
    const int j = i - 507;
    const int a = j / 676;
    rem = j % 676;
    HW = 676;
    W = 26;
    const float AW[3] = {10.f, 23.f, 37.f};
    const float AH[3] = {14.f, 27.f, 58.f};
    aw = AW[a];
    ah = AH[a];
    p = feat2 + ((size_t)b * 255 + a * 85) * 676 + rem;
  }
  const int gy = rem / W, gx = rem % W;
  const float invW = 1.0f / (float)W;
  float cx = (sig_(p[0]) + (float)gx) * invW;
  float cy = (sig_(p[(size_t)HW]) + (float)gy) * invW;
  float bw = expf(p[(size_t)2 * HW]) * aw / 416.0f;
  float bh = expf(p[(size_t)3 * HW]) * ah / 416.0f;
  float obj = sig_(p[(size_t)4 * HW]);
  float best = p[(size_t)5 * HW];
  int lab = 0;
  for (int c = 1; c < 80; ++c) {
    float v = p[(size_t)(5 + c) * HW];
    if (v > best) {
      best = v;
      lab = c;
    }
  }
  float cc = sig_(best);
  float score = obj * cc;
  if (score < 0.1f) score = 0.0f;
  float* o = cand + (size_t)gid * 8;
  o[0] = (cy - bh * 0.5f) * 416.0f;
  o[1] = (cx - bw * 0.5f) * 416.0f;
  o[2] = (cy + bh * 0.5f) * 416.0f;
  o[3] = (cx + bw * 0.5f) * 416.0f;
  o[4] = obj;
  o[5] = cc;
  o[6] = (float)lab;
  o[7] = score;
  keys[gid] = ((u64)__float_as_uint(score) << 32) |
              (u64)(0xFFFFFFFFu - (unsigned)i);
}

// ---------------------------------------------------------------------------
// Exact top-300 via rank (distinct keys -> bijection): sel[rank]=idx.
// ---------------------------------------------------------------------------
__global__ __launch_bounds__(256) void rank_select_kernel(
    const u64* __restrict__ keys, int* __restrict__ sel) {
  const int b = blockIdx.y;
  __shared__ u64 k[NCAND];
  const u64* kb = keys + (size_t)b * NCAND;
  for (int t = threadIdx.x; t < NCAND; t += 256) k[t] = kb[t];
  __syncthreads();
  const int idx = blockIdx.x * 256 + threadIdx.x;
  if (idx >= NCAND) return;
  const u64 me = k[idx];
  int rank = 0;
#pragma unroll 4
  for (int j = 0; j < NCAND; j++) rank += (k[j] > me) ? 1 : 0;
  if (rank < NKEEP) sel[b * NKEEP + rank] = idx;
}

// ---------------------------------------------------------------------------
// Per-image NMS. Forward suppression rows supT[i] = { j>i : same label, both
// valid, IoU>0.5 } (== reference sup transposed; IoU/label symmetric).
// Greedy recursion: kw init = valid; for i asc: if kw[i] then kw &= ~supT[i].
// Identical to the reference fori_loop (keep[j] final before i reads it).
// Scan is single-thread but with depth-3 rolling register prefetch of rows
// (static addresses) -> LDS-throughput-bound, not latency-bound.
// ---------------------------------------------------------------------------
__global__ __launch_bounds__(256) void nms_kernel(
    const float* __restrict__ cand, const int* __restrict__ sel,
    float* __restrict__ out) {
  const int b = blockIdx.x;
  const int tid = threadIdx.x;
  const float* cb = cand + (size_t)b * NCAND * 8;

  __shared__ float4 bxv[NKEEP];
  __shared__ float2 oc2[NKEEP];
  __shared__ int lv[NKEEP];  // label | (valid << 16)
  __shared__ u64 msk[NKEEP][6];  // row stride 48B (16B-aligned rows)
  __shared__ u64 validw[5];
  __shared__ u64 keepw[5];

  for (int t = tid; t < NKEEP; t += 256) {
    const int idx = sel[b * NKEEP + t];
    const float* c = cb + (size_t)idx * 8;
    const float4 c0 = *(const float4*)c;
    const float4 c1 = *(const float4*)(c + 4);
    bxv[t] = c0;
    oc2[t] = make_float2(c1.x, c1.y);
    lv[t] = (int)c1.z | ((c1.w > 0.0f) ? 0x10000 : 0);
  }
  __syncthreads();

  // valid bitmask via per-wave ballots (waves 0..3 -> words 0..3; wave 0's
  // second ballot covers t = 256..299 -> word 4).
  {
    const u64 m1 = __ballot((lv[tid] & 0x10000) != 0);
    if ((tid & 63) == 0) validw[tid >> 6] = m1;
    const u64 m2 = __ballot(tid < 44 && (lv[tid + 256] & 0x10000) != 0);
    if (tid == 0) validw[4] = m2;
  }

  // Build supT rows (upper triangle only).
  for (int t = tid; t < NKEEP; t += 256) {
    u64 w[5] = {0, 0, 0, 0, 0};
    const int lvt = lv[t];
    if (lvt & 0x10000) {
      const float4 a = bxv[t];
      const float aarea = (a.z - a.x) * (a.w - a.y);
#pragma unroll 2
      for (int j = t + 1; j < NKEEP; j++) {
        if (lv[j] != lvt) continue;  // same label AND valid (lvt has bit set)
        const float4 bb = bxv[j];
        const float ty = fmaxf(a.x, bb.x), tx = fmaxf(a.y, bb.y);
        const float ey = fminf(a.z, bb.z), ex = fminf(a.w, bb.w);
        const float dy = fmaxf(ey - ty, 0.0f), dx = fmaxf(ex - tx, 0.0f);
        const float inter = dy * dx;
        const float barea = (bb.z - bb.x) * (bb.w - bb.y);
        const float iou = inter / (aarea + barea - inter + 1e-9f);
        if (iou > 0.5f) w[j >> 6] |= 1ull << (j & 63);
      }
    }
#pragma unroll
    for (int q = 0; q < 5; q++) msk[t][q] = w[q];
  }
  __syncthreads();

  if (tid == 0) {
    u64 kw[5];
#pragma unroll
    for (int q = 0; q < 5; q++) kw[q] = validw[q];
    u64 pre[3][5];
#pragma unroll
    for (int d = 0; d < 3; d++)
#pragma unroll
      for (int q = 0; q < 5; q++) pre[d][q] = msk[d][q];
    for (int i = 0; i < NKEEP; i++) {
      u64 row[5];
#pragma unroll
      for (int q = 0; q < 5; q++) row[q] = pre[0][q];
#pragma unroll
      for (int d = 0; d < 2; d++)
#pragma unroll
        for (int q = 0; q < 5; q++) pre[d][q] = pre[d + 1][q];
      if (i + 3 < NKEEP) {
#pragma unroll
        for (int q = 0; q < 5; q++) pre[2][q] = msk[i + 3][q];
      }
      const u64 bit = (kw[i >> 6] >> (i & 63)) & 1ull;
      const u64 m = 0ull - bit;  // all-ones if kept
#pragma unroll
      for (int q = 0; q < 5; q++) kw[q] &= ~(row[q] & m);
    }
#pragma unroll
    for (int q = 0; q < 5; q++) keepw[q] = kw[q];
  }
  __syncthreads();

  float* ob = out + (size_t)b * NKEEP * 7;
  for (int t = tid; t < NKEEP; t += 256) {
    const bool k = (keepw[t >> 6] >> (t & 63)) & 1ull;
    float* r = ob + (size_t)t * 7;
    if (k) {
      const float4 a = bxv[t];
      const float2 o2 = oc2[t];
      r[0] = a.x;
      r[1] = a.y;
      r[2] = a.z;
      r[3] = a.w;
      r[4] = o2.x;
      r[5] = o2.y;
      r[6] = (float)(lv[t] & 0xFFFF);
    } else {
      r[0] = 0.0f; r[1] = 0.0f; r[2] = 0.0f; r[3] = 0.0f;
      r[4] = 0.0f; r[5] = 0.0f; r[6] = 0.0f;
    }
  }
}

// ---------------------------------------------------------------------------
// Workspace (float offsets):
//   X1 : [0, 11075584)         8*32*208*208
//   X2 : [11075584, 16613376)  8*64*104*104  (region reused as P afterwards)
//   X3 : [0, 2768896)
//   X4 : [2768896, 4153344)
//   F2 : [4153344, 5532384)
//   X5 : [5532384, 6224608)
//   F1 : [6224608, 6569368)
//   CD : [6569368, 6731608)
//   KEY: [6731608, 6772168)
//   SEL: [6772168, 6774568)
//   P  : [11075584, +5537792)  max partial use = 5,516,160 floats (head2 x4)
// Peak = 16613376 floats = 66.5 MB.
// ---------------------------------------------------------------------------
extern "C" void kernel_launch(void* const* d_in, const int* in_sizes, int n_in,
                              void* d_out, int out_size, void* d_ws,
                              size_t ws_size, hipStream_t stream) {
  const float* images = (const float*)d_in[0];
  const float* w1 = (const float*)d_in[1];
  const float* b1 = (const float*)d_in[2];
  const float* w2 = (const float*)d_in[3];
  const float* b2 = (const float*)d_in[4];
  const float* w3 = (const float*)d_in[5];
  const float* b3 = (const float*)d_in[6];
  const float* w4 = (const float*)d_in[7];
  const float* b4 = (const float*)d_in[8];
  const float* w5 = (const float*)d_in[9];
  const float* b5 = (const float*)d_in[10];
  const float* wh1 = (const float*)d_in[11];
  const float* bh1 = (const float*)d_in[12];
  const float* wh2 = (const float*)d_in[13];
  const float* bh2 = (const float*)d_in[14];
  float* ws = (float*)d_ws;

  float* x1 = ws + 0;
  float* x2 = ws + 11075584;
  float* x3 = ws + 0;
  float* x4 = ws + 2768896;
  float* f2 = ws + 4153344;
  float* x5 = ws + 5532384;
  float* f1 = ws + 6224608;
  float* cd = ws + 6569368;
  u64* keys = (u64*)(ws + 6731608);
  int* sel = (int*)(ws + 6772168);
  float* P = ws + 11075584;

  // conv1: pairs=208*104=21632 -> 2720 blocks
  conv3x3s2_p2<3, 416, 416, 8, 1><<<dim3(85, 4, 8), 256, 0, stream>>>(images, w1, b1, x1);
  // conv2: pairs=104*52=5408 -> 1408 blocks
  conv3x3s2_p2<32, 208, 208, 8, 1><<<dim3(22, 8, 8), 256, 0, stream>>>(x1, w2, b2, x2);
  // conv3: pairs=52*26=1352 -> 768 blocks
  conv3x3s2_p2<64, 104, 104, 8, 1><<<dim3(6, 16, 8), 256, 0, stream>>>(x2, w3, b3, x3);
  // conv4: pairs=26*13=338, split-K x2 -> 1024 blocks
  conv3x3s2_p2<128, 52, 52, 8, 2><<<dim3(2, 32, 16), 256, 0, stream>>>(x3, w4, nullptr, P);
  reduce_bias<2, true><<<(1384448 + 255) / 256, 256, 0, stream>>>(P, b4, x4, 256, 676, 1384448);
  // head2: split-K x4 -> 1440 blocks
  conv1x1_part<256, 17, 4><<<dim3(3, 15, 32), 256, 0, stream>>>(x4, wh2, P, 676);
  reduce_bias<4, false><<<(1379040 + 255) / 256, 256, 0, stream>>>(P, bh2, f2, 255, 676, 1379040);
  // conv5 (WOUT=13 odd): single-spatial, split-K x4 -> 2048 blocks
  conv3x3s2<256, 26, 26, 8, 4><<<dim3(1, 64, 32), 256, 0, stream>>>(x4, w5, nullptr, P);
  reduce_bias<4, true><<<(692224 + 255) / 256, 256, 0, stream>>>(P, b5, x5, 512, 169, 692224);
  // head1: split-K x8 -> 960 blocks
  conv1x1_part<512, 17, 8><<<dim3(1, 15, 64), 256, 0, stream>>>(x5, wh1, P, 169);
  reduce_bias<8, false><<<(344760 + 255) / 256, 256, 0, stream>>>(P, bh1, f1, 255, 169, 344760);

  decode_kernel<<<80, 256, 0, stream>>>(f1, f2, cd, keys);
  rank_select_kernel<<<dim3(10, 8), 256, 0, stream>>>(keys, sel);
  nms_kernel<<<8, 256, 0, stream>>>(cd, sel, (float*)d_out);
}

// Round 6
// 641.994 us; speedup vs baseline: 1.4157x; 1.0307x over previous
//
#include <hip/hip_runtime.h>
#include <stdint.h>

typedef unsigned long long u64;

__device__ __forceinline__ float sig_(float x) { return 1.0f / (1.0f + expf(-x)); }

#define NCAND 2535
#define NKEEP 300

// ---------------------------------------------------------------------------
// Pair-spatial 3x3 stride-2 conv (2 horizontal outputs/thread), SAME padding
// (0 before / 1 after), OCT out-channels/thread, deterministic split-K.
// Window = 3 rows x 5 cols; rows loaded as aligned float4 + predicated
// scalar. Register double-buffer over ci. Requires WOUT even, WIN % 4 == 0.
// ---------------------------------------------------------------------------
template <int CIN, int HIN, int WIN, int OCT, int SPLIT>
__global__ __launch_bounds__(256) void conv3x3s2_p2(
    const float* __restrict__ in, const float* __restrict__ wgt,
    const float* __restrict__ bias, float* __restrict__ out) {
  constexpr int HOUT = HIN / 2, WOUT = WIN / 2;
  constexpr int WP = WOUT / 2;
  constexpr int HWIN = HIN * WIN, HWOUT = HOUT * WOUT;
  constexpr int CS = CIN / SPLIT;
  static_assert(WOUT % 2 == 0 && WIN % 4 == 0, "pair kernel layout");
  const int b = blockIdx.z / SPLIT;
  const int s = blockIdx.z % SPLIT;
  const int oc0 = blockIdx.y * OCT;
  const int COUT = gridDim.y * OCT;
  const int sp = blockIdx.x * 256 + threadIdx.x;
  if (sp >= HOUT * WP) return;
  const int oy = sp / WP, oxp = sp % WP;
  const int ox0 = oxp * 2;
  const int iy0 = oy * 2, ix0 = oxp * 4;
  const bool okY = (iy0 + 2 < HIN);
  const bool c4v = (ix0 + 4 < WIN);
  const float* inb =
      in + ((size_t)b * CIN + s * CS) * HWIN + (size_t)iy0 * WIN + ix0;
  const float* wbase = wgt + ((size_t)oc0 * CIN + s * CS) * 9;

  float acc0[OCT], acc1[OCT];
#pragma unroll
  for (int u = 0; u < OCT; u++) {
    acc0[u] = 0.0f;
    acc1[u] = 0.0f;
  }

  auto load15 = [&](float v[15], const float* ip) {
#pragma unroll
    for (int ky = 0; ky < 3; ky++) {
      const bool rok = (ky < 2) || okY;
      const float* rp = ip + ky * WIN;
      float4 p = make_float4(0.f, 0.f, 0.f, 0.f);
      float c4 = 0.f;
      if (rok) {
        p = *(const float4*)rp;  // 16B-aligned: ix0%4==0, WIN%4==0
        if (c4v) c4 = rp[4];
      }
      v[ky * 5 + 0] = p.x;
      v[ky * 5 + 1] = p.y;
      v[ky * 5 + 2] = p.z;
      v[ky * 5 + 3] = p.w;
      v[ky * 5 + 4] = c4;
    }
  };

  float cur[15];
  load15(cur, inb);

  for (int ci = 0; ci < CS; ++ci) {
    float nxt[15];
    const bool more = (ci + 1 < CS);
    if (more) load15(nxt, inb + (size_t)(ci + 1) * HWIN);
    const float* wp = wbase + (size_t)ci * 9;
#pragma unroll
    for (int u = 0; u < OCT; u++) {
#pragma unroll
      for (int ky = 0; ky < 3; ky++) {
#pragma unroll
        for (int kx = 0; kx < 3; kx++) {
          const float w = wp[(size_t)u * CIN * 9 + ky * 3 + kx];
          acc0[u] = fmaf(cur[ky * 5 + kx], w, acc0[u]);
          acc1[u] = fmaf(cur[ky * 5 + kx + 2], w, acc1[u]);
        }
      }
    }
    if (more) {
#pragma unroll
      for (int k = 0; k < 15; k++) cur[k] = nxt[k];
    }
  }

  const size_t obase =
      (SPLIT == 1 ? (size_t)b * COUT : (size_t)(s * 8 + b) * COUT);
  float* ob = out + (obase + oc0) * HWOUT + (size_t)oy * WOUT + ox0;
  if (SPLIT == 1) {
#pragma unroll
    for (int u = 0; u < OCT; u++) {
      float r0 = acc0[u] + bias[oc0 + u];
      float r1 = acc1[u] + bias[oc0 + u];
      r0 = r0 > 0.0f ? r0 : 0.1f * r0;
      r1 = r1 > 0.0f ? r1 : 0.1f * r1;
      *(float2*)(ob + (size_t)u * HWOUT) = make_float2(r0, r1);
    }
  } else {
#pragma unroll
    for (int u = 0; u < OCT; u++)
      *(float2*)(ob + (size_t)u * HWOUT) = make_float2(acc0[u], acc1[u]);
  }
}

// ---------------------------------------------------------------------------
// Single-spatial 3x3 stride-2 conv (conv5: WOUT=13 odd).
// ---------------------------------------------------------------------------
template <int WIN>
__device__ __forceinline__ void load9(float v[9], const float* __restrict__ ip,
                                      bool okY, bool okX) {
#pragma unroll
  for (int ky = 0; ky < 3; ky++) {
    const bool rok = (ky < 2) || okY;
    const float* rp = ip + ky * WIN;
    float a0 = 0.0f, a1 = 0.0f, a2 = 0.0f;
    if (rok) {
      const float2 p = *(const float2*)rp;  // 8B-aligned
      a0 = p.x;
      a1 = p.y;
      if (okX) a2 = rp[2];
    }
    v[ky * 3 + 0] = a0;
    v[ky * 3 + 1] = a1;
    v[ky * 3 + 2] = a2;
  }
}

template <int CIN, int HIN, int WIN, int OCT, int SPLIT>
__global__ __launch_bounds__(256) void conv3x3s2(
    const float* __restrict__ in, const float* __restrict__ wgt,
    const float* __restrict__ bias, float* __restrict__ out) {
  constexpr int HOUT = HIN / 2, WOUT = WIN / 2;
  constexpr int HWIN = HIN * WIN, HWOUT = HOUT * WOUT;
  constexpr int CS = CIN / SPLIT;
  const int b = blockIdx.z / SPLIT;
  const int s = blockIdx.z % SPLIT;
  const int oc0 = blockIdx.y * OCT;
  const int COUT = gridDim.y * OCT;
  const int sp = blockIdx.x * 256 + threadIdx.x;
  if (sp >= HWOUT) return;
  const int oy = sp / WOUT, ox = sp % WOUT;
  const int iy0 = oy * 2, ix0 = ox * 2;
  const bool okY = (iy0 + 2 < HIN);
  const bool okX = (ix0 + 2 < WIN);
  const float* inb =
      in + ((size_t)b * CIN + s * CS) * HWIN + (size_t)iy0 * WIN + ix0;
  const float* wbase = wgt + ((size_t)oc0 * CIN + s * CS) * 9;

  float acc[OCT];
#pragma unroll
  for (int u = 0; u < OCT; u++) acc[u] = 0.0f;

  float cur[9];
  load9<WIN>(cur, inb, okY, okX);

  for (int ci = 0; ci < CS; ++ci) {
    float nxt[9];
    const bool more = (ci + 1 < CS);
    if (more) load9<WIN>(nxt, inb + (size_t)(ci + 1) * HWIN, okY, okX);
    const float* wp = wbase + (size_t)ci * 9;
#pragma unroll
    for (int u = 0; u < OCT; u++) {
#pragma unroll
      for (int k = 0; k < 9; k++)
        acc[u] = fmaf(cur[k], wp[(size_t)u * CIN * 9 + k], acc[u]);
    }
    if (more) {
#pragma unroll
      for (int k = 0; k < 9; k++) cur[k] = nxt[k];
    }
  }

  if (SPLIT == 1) {
    float* ob = out + ((size_t)b * COUT + oc0) * HWOUT + sp;
#pragma unroll
    for (int u = 0; u < OCT; u++) {
      float r = acc[u] + bias[oc0 + u];
      r = r > 0.0f ? r : 0.1f * r;
      ob[(size_t)u * HWOUT] = r;
    }
  } else {
    float* ob = out + ((size_t)(s * 8 + b) * COUT + oc0) * HWOUT + sp;
#pragma unroll
    for (int u = 0; u < OCT; u++) ob[(size_t)u * HWOUT] = acc[u];
  }
}

// ---------------------------------------------------------------------------
// 1x1 conv partials (COUT=255 total), OCT ch/thread, split-K slice s.
// ---------------------------------------------------------------------------
template <int CIN, int OCT, int SPLIT>
__global__ __launch_bounds__(256) void conv1x1_part(
    const float* __restrict__ in, const float* __restrict__ wgt,
    float* __restrict__ out, int HW) {
  constexpr int CS = CIN / SPLIT;
  const int sp = blockIdx.x * 256 + threadIdx.x;
  if (sp >= HW) return;
  const int oc0 = blockIdx.y * OCT;
  const int b = blockIdx.z / SPLIT;
  const int s = blockIdx.z % SPLIT;
  const float* ip = in + ((size_t)b * CIN + s * CS) * HW + sp;
  const float* wb = wgt + s * CS;
  float acc[OCT];
#pragma unroll
  for (int u = 0; u < OCT; u++) acc[u] = 0.0f;

  float cur[4];
#pragma unroll
  for (int j = 0; j < 4; j++) cur[j] = ip[(size_t)j * HW];

  for (int c0 = 0; c0 < CS; c0 += 4) {
    float nxt[4];
    const bool more = (c0 + 4 < CS);
    if (more) {
#pragma unroll
      for (int j = 0; j < 4; j++) nxt[j] = ip[(size_t)(c0 + 4 + j) * HW];
    }
#pragma unroll
    for (int j = 0; j < 4; j++) {
#pragma unroll
      for (int u = 0; u < OCT; u++)
        acc[u] = fmaf(cur[j], wb[(size_t)(oc0 + u) * CIN + c0 + j], acc[u]);
    }
    if (more) {
#pragma unroll
      for (int j = 0; j < 4; j++) cur[j] = nxt[j];
    }
  }
#pragma unroll
  for (int u = 0; u < OCT; u++)
    out[((size_t)(s * 8 + b) * 255 + oc0 + u) * HW + sp] = acc[u];
}

// ---------------------------------------------------------------------------
// Reduce SPLIT partials (slice-major, deterministic) + bias (+ lrelu).
// ---------------------------------------------------------------------------
template <int SPLIT, bool LRELU>
__global__ __launch_bounds__(256) void reduce_bias(
    const float* __restrict__ P, const float* __restrict__ bias,
    float* __restrict__ out, int COUT, int HWOUT, int N) {
  const int gid = blockIdx.x * 256 + threadIdx.x;
  if (gid >= N) return;
  float a = 0.0f;
#pragma unroll
  for (int s = 0; s < SPLIT; s++) a += P[(size_t)s * N + gid];
  const int oc = (gid / HWOUT) % COUT;
  a += bias[oc];
  if (LRELU) a = a > 0.0f ? a : 0.1f * a;
  out[gid] = a;
}

// ---------------------------------------------------------------------------
// Decode both heads -> cand[b][i][8] = {y1,x1,y2,x2,obj,cc,label,score} and
// packed keys (score_bits<<32)|(0xFFFFFFFF-i) matching jax.lax.top_k order.
// ---------------------------------------------------------------------------
__global__ __launch_bounds__(256) void decode_kernel(
    const float* __restrict__ feat1, const float* __restrict__ feat2,
    float* __restrict__ cand, u64* __restrict__ keys) {
  const int gid = blockIdx.x * 256 + threadIdx.x;
  if (gid >= 8 * NCAND) return;
  const int b = gid / NCAND;
  const int i = gid % NCAND;
  const float* p;
  int rem, HW, W;
  float aw, ah;
  if (i < 507) {
    const int a = i / 169;
    rem = i % 169;
    HW = 169;
    W = 13;
    const float AW[3] = {81.f, 135.f, 344.f};
    const float AH[3] = {82.f, 169.f, 319.f};
    aw = AW[a];
    ah = AH[a];
    p = feat1 + ((size_t)b * 255 + a * 85) * 169 + rem;
  } else {
    const int j = i - 507;
    const int a = j / 676;
    rem = j % 676;
    HW = 676;
    W = 26;
    const float AW[3] = {10.f, 23.f, 37.f};
    const float AH[3] = {14.f, 27.f, 58.f};
    aw = AW[a];
    ah = AH[a];
    p = feat2 + ((size_t)b * 255 + a * 85) * 676 + rem;
  }
  const int gy = rem / W, gx = rem % W;
  const float invW = 1.0f / (float)W;
  float cx = (sig_(p[0]) + (float)gx) * invW;
  float cy = (sig_(p[(size_t)HW]) + (float)gy) * invW;
  float bw = expf(p[(size_t)2 * HW]) * aw / 416.0f;
  float bh = expf(p[(size_t)3 * HW]) * ah / 416.0f;
  float obj = sig_(p[(size_t)4 * HW]);
  float best = p[(size_t)5 * HW];
  int lab = 0;
  for (int c = 1; c < 80; ++c) {
    float v = p[(size_t)(5 + c) * HW];
    if (v > best) {
      best = v;
      lab = c;
    }
  }
  float cc = sig_(best);
  float score = obj * cc;
  if (score < 0.1f) score = 0.0f;
  float* o = cand + (size_t)gid * 8;
  o[0] = (cy - bh * 0.5f) * 416.0f;
  o[1] = (cx - bw * 0.5f) * 416.0f;
  o[2] = (cy + bh * 0.5f) * 416.0f;
  o[3] = (cx + bw * 0.5f) * 416.0f;
  o[4] = obj;
  o[5] = cc;
  o[6] = (float)lab;
  o[7] = score;
  keys[gid] = ((u64)__float_as_uint(score) << 32) |
              (u64)(0xFFFFFFFFu - (unsigned)i);
}

// ---------------------------------------------------------------------------
// Exact top-300 via rank (distinct keys -> bijection): sel[rank]=idx.
// ---------------------------------------------------------------------------
__global__ __launch_bounds__(256) void rank_select_kernel(
    const u64* __restrict__ keys, int* __restrict__ sel) {
  const int b = blockIdx.y;
  __shared__ u64 k[NCAND];
  const u64* kb = keys + (size_t)b * NCAND;
  for (int t = threadIdx.x; t < NCAND; t += 256) k[t] = kb[t];
  __syncthreads();
  const int idx = blockIdx.x * 256 + threadIdx.x;
  if (idx >= NCAND) return;
  const u64 me = k[idx];
  int rank = 0;
#pragma unroll 4
  for (int j = 0; j < NCAND; j++) rank += (k[j] > me) ? 1 : 0;
  if (rank < NKEEP) sel[b * NKEEP + rank] = idx;
}

// ---------------------------------------------------------------------------
// Per-image NMS. supT[i] = { j>i : same label, both valid, IoU>0.5 }.
// Greedy recursion: kw init = valid; for i asc: if kw[i] then kw &= ~supT[i]
// == reference fori_loop (keep[j] final before i reads it; sup symmetric).
// Scan keeps ALL state in NAMED scalar registers (no dynamic register
// indexing -> no scratch spill; round-5's kw[i>>6] cost 880 cyc/iter).
// Word selection is compile-time via 5 lambda instantiations; mask rows come
// from LDS with a depth-1 rolling register prefetch.
// ---------------------------------------------------------------------------
__global__ __launch_bounds__(256) void nms_kernel(
    const float* __restrict__ cand, const int* __restrict__ sel,
    float* __restrict__ out) {
  const int b = blockIdx.x;
  const int tid = threadIdx.x;
  const float* cb = cand + (size_t)b * NCAND * 8;

  __shared__ float4 bxv[NKEEP];
  __shared__ float2 oc2[NKEEP];
  __shared__ int lv[NKEEP];      // label | (valid << 16)
  __shared__ u64 msk[NKEEP][6];  // row stride 48B (16B-aligned rows)
  __shared__ u64 validw[5];
  __shared__ u64 keepw[5];

  for (int t = tid; t < NKEEP; t += 256) {
    const int idx = sel[b * NKEEP + t];
    const float* c = cb + (size_t)idx * 8;
    const float4 c0 = *(const float4*)c;
    const float4 c1 = *(const float4*)(c + 4);
    bxv[t] = c0;
    oc2[t] = make_float2(c1.x, c1.y);
    lv[t] = (int)c1.z | ((c1.w > 0.0f) ? 0x10000 : 0);
  }
  __syncthreads();

  {
    const u64 m1 = __ballot((lv[tid] & 0x10000) != 0);
    if ((tid & 63) == 0) validw[tid >> 6] = m1;
    const u64 m2 = __ballot(tid < 44 && (lv[tid + 256] & 0x10000) != 0);
    if (tid == 0) validw[4] = m2;
  }

  // Build supT rows (upper triangle only).
  for (int t = tid; t < NKEEP; t += 256) {
    u64 w[5] = {0, 0, 0, 0, 0};
    const int lvt = lv[t];
    if (lvt & 0x10000) {
      const float4 a = bxv[t];
      const float aarea = (a.z - a.x) * (a.w - a.y);
#pragma unroll 2
      for (int j = t + 1; j < NKEEP; j++) {
        if (lv[j] != lvt) continue;  // same label AND valid
        const float4 bb = bxv[j];
        const float ty = fmaxf(a.x, bb.x), tx = fmaxf(a.y, bb.y);
        const float ey = fminf(a.z, bb.z), ex = fminf(a.w, bb.w);
        const float dy = fmaxf(ey - ty, 0.0f), dx = fmaxf(ex - tx, 0.0f);
        const float inter = dy * dx;
        const float barea = (bb.z - bb.x) * (bb.w - bb.y);
        const float iou = inter / (aarea + barea - inter + 1e-9f);
        if (iou > 0.5f) w[j >> 6] |= 1ull << (j & 63);
      }
    }
#pragma unroll
    for (int q = 0; q < 5; q++) msk[t][q] = w[q];
  }
  __syncthreads();

  if (tid == 0) {
    u64 kw0 = validw[0], kw1 = validw[1], kw2 = validw[2], kw3 = validw[3],
        kw4 = validw[4];
    // Rolling prefetch: r* holds row i, loaded one iteration ahead.
    u64 r0 = msk[0][0], r1 = msk[0][1], r2 = msk[0][2], r3 = msk[0][3],
        r4 = msk[0][4];
    auto section = [&](u64& kwq, int base, int nbits) {
      for (int bit = 0; bit < nbits; ++bit) {
        const int i = base + bit;
        u64 n0 = 0, n1 = 0, n2 = 0, n3 = 0, n4 = 0;
        if (i + 1 < NKEEP) {
          n0 = msk[i + 1][0];
          n1 = msk[i + 1][1];
          n2 = msk[i + 1][2];
          n3 = msk[i + 1][3];
          n4 = msk[i + 1][4];
        }
        const u64 m = 0ull - ((kwq >> bit) & 1ull);  // all-ones if i kept
        kw0 &= ~(r0 & m);
        kw1 &= ~(r1 & m);
        kw2 &= ~(r2 & m);
        kw3 &= ~(r3 & m);
        kw4 &= ~(r4 & m);
        r0 = n0; r1 = n1; r2 = n2; r3 = n3; r4 = n4;
      }
    };
    section(kw0, 0, 64);
    section(kw1, 64, 64);
    section(kw2, 128, 64);
    section(kw3, 192, 64);
    section(kw4, 256, 44);
    keepw[0] = kw0;
    keepw[1] = kw1;
    keepw[2] = kw2;
    keepw[3] = kw3;
    keepw[4] = kw4;
  }
  __syncthreads();

  float* ob = out + (size_t)b * NKEEP * 7;
  for (int t = tid; t < NKEEP; t += 256) {
    const bool k = (keepw[t >> 6] >> (t & 63)) & 1ull;
    float* r = ob + (size_t)t * 7;
    if (k) {
      const float4 a = bxv[t];
      const float2 o2 = oc2[t];
      r[0] = a.x;
      r[1] = a.y;
      r[2] = a.z;
      r[3] = a.w;
      r[4] = o2.x;
      r[5] = o2.y;
      r[6] = (float)(lv[t] & 0xFFFF);
    } else {
      r[0] = 0.0f; r[1] = 0.0f; r[2] = 0.0f; r[3] = 0.0f;
      r[4] = 0.0f; r[5] = 0.0f; r[6] = 0.0f;
    }
  }
}

// ---------------------------------------------------------------------------
// Workspace (float offsets):
//   X1 : [0, 11075584)         8*32*208*208
//   X2 : [11075584, 16613376)  8*64*104*104  (region reused as P afterwards)
//   X3 : [0, 2768896)
//   X4 : [2768896, 4153344)
//   F2 : [4153344, 5532384)
//   X5 : [5532384, 6224608)
//   F1 : [6224608, 6569368)
//   CD : [6569368, 6731608)
//   KEY: [6731608, 6772168)
//   SEL: [6772168, 6774568)
//   P  : [11075584, +5537792)  max partial use = 5,516,160 floats (head2 x4)
// Peak = 16613376 floats = 66.5 MB.
// ---------------------------------------------------------------------------
extern "C" void kernel_launch(void* const* d_in, const int* in_sizes, int n_in,
                              void* d_out, int out_size, void* d_ws,
                              size_t ws_size, hipStream_t stream) {
  const float* images = (const float*)d_in[0];
  const float* w1 = (const float*)d_in[1];
  const float* b1 = (const float*)d_in[2];
  const float* w2 = (const float*)d_in[3];
  const float* b2 = (const float*)d_in[4];
  const float* w3 = (const float*)d_in[5];
  const float* b3 = (const float*)d_in[6];
  const float* w4 = (const float*)d_in[7];
  const float* b4 = (const float*)d_in[8];
  const float* w5 = (const float*)d_in[9];
  const float* b5 = (const float*)d_in[10];
  const float* wh1 = (const float*)d_in[11];
  const float* bh1 = (const float*)d_in[12];
  const float* wh2 = (const float*)d_in[13];
  const float* bh2 = (const float*)d_in[14];
  float* ws = (float*)d_ws;

  float* x1 = ws + 0;
  float* x2 = ws + 11075584;
  float* x3 = ws + 0;
  float* x4 = ws + 2768896;
  float* f2 = ws + 4153344;
  float* x5 = ws + 5532384;
  float* f1 = ws + 6224608;
  float* cd = ws + 6569368;
  u64* keys = (u64*)(ws + 6731608);
  int* sel = (int*)(ws + 6772168);
  float* P = ws + 11075584;

  // conv1: pairs=208*104=21632 -> 2720 blocks
  conv3x3s2_p2<3, 416, 416, 8, 1><<<dim3(85, 4, 8), 256, 0, stream>>>(images, w1, b1, x1);
  // conv2: pairs=104*52=5408 -> 1408 blocks
  conv3x3s2_p2<32, 208, 208, 8, 1><<<dim3(22, 8, 8), 256, 0, stream>>>(x1, w2, b2, x2);
  // conv3: pairs=52*26=1352 -> 768 blocks
  conv3x3s2_p2<64, 104, 104, 8, 1><<<dim3(6, 16, 8), 256, 0, stream>>>(x2, w3, b3, x3);
  // conv4: pairs=26*13=338, split-K x2 -> 1024 blocks
  conv3x3s2_p2<128, 52, 52, 8, 2><<<dim3(2, 32, 16), 256, 0, stream>>>(x3, w4, nullptr, P);
  reduce_bias<2, true><<<(1384448 + 255) / 256, 256, 0, stream>>>(P, b4, x4, 256, 676, 1384448);
  // head2: split-K x4 -> 1440 blocks
  conv1x1_part<256, 17, 4><<<dim3(3, 15, 32), 256, 0, stream>>>(x4, wh2, P, 676);
  reduce_bias<4, false><<<(1379040 + 255) / 256, 256, 0, stream>>>(P, bh2, f2, 255, 676, 1379040);
  // conv5 (WOUT=13 odd): single-spatial, split-K x4 -> 2048 blocks
  conv3x3s2<256, 26, 26, 8, 4><<<dim3(1, 64, 32), 256, 0, stream>>>(x4, w5, nullptr, P);
  reduce_bias<4, true><<<(692224 + 255) / 256, 256, 0, stream>>>(P, b5, x5, 512, 169, 692224);
  // head1: split-K x8 -> 960 blocks
  conv1x1_part<512, 17, 8><<<dim3(1, 15, 64), 256, 0, stream>>>(x5, wh1, P, 169);
  reduce_bias<8, false><<<(344760 + 255) / 256, 256, 0, stream>>>(P, bh1, f1, 255, 169, 344760);

  decode_kernel<<<80, 256, 0, stream>>>(f1, f2, cd, keys);
  rank_select_kernel<<<dim3(10, 8), 256, 0, stream>>>(keys, sel);
  nms_kernel<<<8, 256, 0, stream>>>(cd, sel, (float*)d_out);
}